// Round 8
// baseline (435.790 us; speedup 1.0000x reference)
//
#include <hip/hip_runtime.h>
#include <hip/hip_bf16.h>

#define DIM 512
#define BATCH 512
#define CCLS 100000
#define BM 128
#define BN 128
#define NT 782   // ceil(100000/128)

typedef __attribute__((ext_vector_type(4))) float f32x4;

__device__ __forceinline__ void async_copy16(const unsigned char* g, unsigned char* l) {
  __builtin_amdgcn_global_load_lds((const __attribute__((address_space(1))) void*)g,
                                   (__attribute__((address_space(3))) void*)l, 16, 0, 0);
}

// One wave per row of x: quantize RAW x to fp8 e4m3 (norms divided out in the
// GEMM epilogue), emit nx[row] = |x_row|.
__global__ __launch_bounds__(256) void xquant(const float* __restrict__ x,
                                              unsigned char* __restrict__ xq,
                                              float* __restrict__ nx) {
  int wave = threadIdx.x >> 6;
  int lane = threadIdx.x & 63;
  int row = blockIdx.x * 4 + wave;           // 512 rows, 128 blocks
  const float4* src = (const float4*)(x + (size_t)row * DIM);
  float4 v0 = src[2 * lane];
  float4 v1 = src[2 * lane + 1];
  float ss = v0.x*v0.x + v0.y*v0.y + v0.z*v0.z + v0.w*v0.w
           + v1.x*v1.x + v1.y*v1.y + v1.z*v1.z + v1.w*v1.w;
  #pragma unroll
  for (int off = 32; off > 0; off >>= 1) ss += __shfl_xor(ss, off, 64);
  int p0 = __builtin_amdgcn_cvt_pk_fp8_f32(v0.x, v0.y, 0, false);
  p0     = __builtin_amdgcn_cvt_pk_fp8_f32(v0.z, v0.w, p0, true);
  int p1 = __builtin_amdgcn_cvt_pk_fp8_f32(v1.x, v1.y, 0, false);
  p1     = __builtin_amdgcn_cvt_pk_fp8_f32(v1.z, v1.w, p1, true);
  ((int2*)(xq + (size_t)row * DIM))[lane] = make_int2(p0, p1);
  if (lane == 0) nx[row] = fmaxf(sqrtf(ss), 1e-12f);
}

// Fused wt-quantize + 128x128 fp8 GEMM + CosFace epilogue.
// Structural fix of R7's latency exposure:
//  - A (xq, L2-resident) staged into LDS ONCE (full K, 64 KB) in the
//    prologue -- per-iter A staging and its barrier drain are gone.
//  - B: 3-stage reg pipeline. iter k: ds_write B(k+1) [quantized last iter,
//    into the dbuf half nobody reads this iter] -> issue f(k+2) loads ->
//    32 MFMA (1240 cy/SIMD, covers ~900 cy HBM) -> quantize f(k+2) ->
//    ONE __syncthreads whose vm/lgkm queues are empty by construction.
//  - nw: each class row owned by one 8-lane group across all K -> plain
//    store after reduce, no atomics.
// 512 threads = 8 waves (2m x 4n), per-wave 64x32, acc[4][2] = 32 AGPR.
// LDS ~98 KB -> 1 block/CU; per-block self-overlap replaces cross-block TLP.
__global__ __launch_bounds__(512, 2) void cosface_fused(
    const unsigned char* __restrict__ xq,
    const float* __restrict__ wt,
    const int* __restrict__ gt,
    const float* __restrict__ nx,
    float* __restrict__ partial,
    float* __restrict__ tgt) {
  __shared__ __align__(16) unsigned char lds_a[BM * DIM];      // 64 KB, full K
  __shared__ __align__(16) unsigned char lds_b[2][BN * 128];   // 32 KB dbuf
  __shared__ float lds_rowsum[BM];
  __shared__ float lds_nx[BM];
  __shared__ float lds_nw[BN];
  __shared__ int lds_gt[BM];

  const int tid = threadIdx.x;
  const int lane = tid & 63;
  const int w = tid >> 6;          // wave 0..7
  const int wm = w >> 2;           // 0..1  (64-row slice)
  const int wn_ = w & 3;           // 0..3  (32-col slice)

  // Bijective XCD swizzle: 3128 = 8*391; the 4 mt-blocks of one nt are
  // f-consecutive on one XCD -> B-tile (wt rows) L2-shared.
  int flat = blockIdx.x;
  int f = (flat & 7) * 391 + (flat >> 3);
  const int mt = f & 3;            // 0..3
  const int nt = f >> 2;           // 0..781

  if (tid < BM) {
    lds_rowsum[tid] = 0.f;
    lds_gt[tid] = gt[mt * BM + tid];
    lds_nx[tid] = nx[mt * BM + tid];
  }

  // ---- A full-K staging: 4096 chunks of 16B, 8/thread, linear LDS dest.
  // chunk c -> row m = c>>5, slot qs = c&31; content chunk within row =
  // (qs&24) | ((qs&7) ^ (m&7))  (XOR swizzle within each 128B k-subblock).
  #pragma unroll
  for (int j = 0; j < 8; ++j) {
    int c = j * 512 + tid;
    int m = c >> 5;
    int qs = c & 31;
    int src = (mt * BM + m) * DIM + (((qs & 24) | ((qs & 7) ^ (m & 7))) << 4);
    async_copy16(xq + src, &lds_a[(j * 512 + w * 64) * 16]);
  }

  // ---- B source mapping: thread owns chunk tid (row r0) and 512+tid (row
  // r1 = r0+64), slot qs = tid&7, content chunk qg = qs ^ (r&7) (r0&7==r1&7).
  const int r0 = tid >> 3;                 // 0..63
  const int r1 = r0 + 64;                  // 64..127
  const int qg = (tid & 7) ^ (r0 & 7);
  int rowB0 = nt * BN + r0; if (rowB0 >= CCLS) rowB0 = CCLS - 1;
  int rowB1 = nt * BN + r1; if (rowB1 >= CCLS) rowB1 = CCLS - 1;
  const float* wsrc0 = wt + (size_t)rowB0 * DIM + qg * 16;
  const float* wsrc1 = wt + (size_t)rowB1 * DIM + qg * 16;

#define LOADB(K) do {                                                        \
    const float* pa_ = wsrc0 + (K) * 128;                                    \
    a0 = *(const float4*)(pa_);     a1 = *(const float4*)(pa_ + 4);          \
    a2 = *(const float4*)(pa_ + 8); a3 = *(const float4*)(pa_ + 12);         \
    const float* pb_ = wsrc1 + (K) * 128;                                    \
    b0 = *(const float4*)(pb_);     b1 = *(const float4*)(pb_ + 4);          \
    b2 = *(const float4*)(pb_ + 8); b3 = *(const float4*)(pb_ + 12);         \
  } while (0)

#define QUANT16(P, SS, F0, F1, F2, F3) do {                                  \
    F0.x*=16.f; F0.y*=16.f; F0.z*=16.f; F0.w*=16.f;                          \
    F1.x*=16.f; F1.y*=16.f; F1.z*=16.f; F1.w*=16.f;                          \
    F2.x*=16.f; F2.y*=16.f; F2.z*=16.f; F2.w*=16.f;                          \
    F3.x*=16.f; F3.y*=16.f; F3.z*=16.f; F3.w*=16.f;                          \
    SS += F0.x*F0.x + F0.y*F0.y + F0.z*F0.z + F0.w*F0.w                      \
        + F1.x*F1.x + F1.y*F1.y + F1.z*F1.z + F1.w*F1.w                      \
        + F2.x*F2.x + F2.y*F2.y + F2.z*F2.z + F2.w*F2.w                      \
        + F3.x*F3.x + F3.y*F3.y + F3.z*F3.z + F3.w*F3.w;                     \
    int q0_ = __builtin_amdgcn_cvt_pk_fp8_f32(F0.x, F0.y, 0, false);         \
    q0_     = __builtin_amdgcn_cvt_pk_fp8_f32(F0.z, F0.w, q0_, true);        \
    int q1_ = __builtin_amdgcn_cvt_pk_fp8_f32(F1.x, F1.y, 0, false);         \
    q1_     = __builtin_amdgcn_cvt_pk_fp8_f32(F1.z, F1.w, q1_, true);        \
    int q2_ = __builtin_amdgcn_cvt_pk_fp8_f32(F2.x, F2.y, 0, false);         \
    q2_     = __builtin_amdgcn_cvt_pk_fp8_f32(F2.z, F2.w, q2_, true);        \
    int q3_ = __builtin_amdgcn_cvt_pk_fp8_f32(F3.x, F3.y, 0, false);         \
    q3_     = __builtin_amdgcn_cvt_pk_fp8_f32(F3.z, F3.w, q3_, true);        \
    P = make_int4(q0_, q1_, q2_, q3_);                                       \
  } while (0)

  f32x4 acc[4][2];
  #pragma unroll
  for (int i = 0; i < 4; ++i)
    #pragma unroll
    for (int j = 0; j < 2; ++j)
      acc[i][j] = (f32x4){0.f, 0.f, 0.f, 0.f};

  const int quad = lane >> 4;
  const int l15 = lane & 15;
  const int sw = l15 & 7;
  float4 a0, a1, a2, a3, b0, b1, b2, b3;
  int4 pA, pB;
  float ss0 = 0.f, ss1 = 0.f;

  // ---- Prologue: quant+write B(0); quant B(1) into regs (exposed once).
  LOADB(0);
  QUANT16(pA, ss0, a0, a1, a2, a3);
  QUANT16(pB, ss1, b0, b1, b2, b3);
  ((int4*)lds_b[0])[tid] = pA;
  ((int4*)lds_b[0])[512 + tid] = pB;
  LOADB(1);
  QUANT16(pA, ss0, a0, a1, a2, a3);
  QUANT16(pB, ss1, b0, b1, b2, b3);
  __syncthreads();   // drains A asyncs + ds_writes; B(0)/A visible

  #pragma unroll
  for (int kk = 0; kk < 4; ++kk) {
    // Publish B(kk+1) into the half nobody reads this iter.
    if (kk < 3) {
      ((int4*)lds_b[(kk + 1) & 1])[tid] = pA;
      ((int4*)lds_b[(kk + 1) & 1])[512 + tid] = pB;
    }
    // Issue f(kk+2) -- lands during the MFMA cluster below.
    if (kk < 2) LOADB(kk + 2);

    // Compute tile kk: A from full-K lds_a, B from lds_b[kk&1].
    #pragma unroll
    for (int s = 0; s < 4; ++s) {
      int g = s * 4 + quad;
      int cs = g >> 1;
      int h = (g & 1) * 8;
      long long af[4], bf[2];
      #pragma unroll
      for (int i = 0; i < 4; ++i)
        af[i] = *(const long long*)&lds_a[(wm * 64 + i * 16 + l15) * DIM + kk * 128 + ((cs ^ sw) * 16) + h];
      #pragma unroll
      for (int j = 0; j < 2; ++j)
        bf[j] = *(const long long*)&lds_b[kk & 1][(wn_ * 32 + j * 16 + l15) * 128 + ((cs ^ sw) * 16) + h];
      #pragma unroll
      for (int i = 0; i < 4; ++i)
        #pragma unroll
        for (int j = 0; j < 2; ++j)
          acc[i][j] = __builtin_amdgcn_mfma_f32_16x16x32_fp8_fp8(af[i], bf[j], acc[i][j], 0, 0, 0);
    }

    // Quantize f(kk+2) (loads covered by the MFMA phase just issued).
    if (kk < 2) {
      QUANT16(pA, ss0, a0, a1, a2, a3);
      QUANT16(pB, ss1, b0, b1, b2, b3);
    }
    if (kk < 3) __syncthreads();   // vm/lgkm queues empty: cheap barrier
  }
#undef LOADB
#undef QUANT16

  // ---- nw: 8-lane group reduce, plain store (one owner per class row).
  ss0 += __shfl_xor(ss0, 1, 64); ss1 += __shfl_xor(ss1, 1, 64);
  ss0 += __shfl_xor(ss0, 2, 64); ss1 += __shfl_xor(ss1, 2, 64);
  ss0 += __shfl_xor(ss0, 4, 64); ss1 += __shfl_xor(ss1, 4, 64);
  if ((lane & 7) == 0) {
    lds_nw[r0] = ss0;
    lds_nw[r1] = ss1;
  }
  __syncthreads();

  // ---- Epilogue: cos = acc/(|16w|*|x|); logit = 64*cos (-22.4 at gt);
  // rowsum += sum_n exp(logit-64).
  float rnw[2];
  #pragma unroll
  for (int j = 0; j < 2; ++j)
    rnw[j] = 1.0f / fmaxf(sqrtf(lds_nw[wn_ * 32 + j * 16 + l15]), 1e-12f);
  #pragma unroll
  for (int i = 0; i < 4; ++i) {
    #pragma unroll
    for (int reg = 0; reg < 4; ++reg) {
      int m_loc = wm * 64 + i * 16 + quad * 4 + reg;
      int gtm = lds_gt[m_loc];
      float rx = 64.0f / lds_nx[m_loc];     // fold SCALE into the division
      float s = 0.f;
      #pragma unroll
      for (int j = 0; j < 2; ++j) {
        int n_g = nt * BN + wn_ * 32 + j * 16 + l15;
        float logit = acc[i][j][reg] * rnw[j] * rx;
        if (n_g == gtm) {
          logit -= 64.f * 0.35f;
          tgt[mt * BM + m_loc] = logit;
        }
        if (n_g < CCLS) s += __expf(logit - 64.f);
      }
      #pragma unroll
      for (int off = 1; off < 16; off <<= 1) s += __shfl_xor(s, off, 64);
      if (l15 == 0) atomicAdd(&lds_rowsum[m_loc], s);
    }
  }
  __syncthreads();
  if (tid < BM)
    partial[(size_t)(mt * BM + tid) * NT + nt] = lds_rowsum[tid];
}

// One wave per row m: sum partial[m][0..NT) (contiguous), emit nll[m].
__global__ __launch_bounds__(64) void nll_rows(const float* __restrict__ partial,
                                               const float* __restrict__ tgt,
                                               float* __restrict__ nll) {
  int m = blockIdx.x;
  int lane = threadIdx.x;
  const float* row = partial + (size_t)m * NT;
  float s = 0.f;
  for (int t = lane; t < NT; t += 64) s += row[t];
  #pragma unroll
  for (int off = 32; off > 0; off >>= 1) s += __shfl_xor(s, off, 64);
  if (lane == 0) nll[m] = (logf(s) + 64.f) - tgt[m];
}

__global__ __launch_bounds__(512) void reduce_mean(const float* __restrict__ nll,
                                                   float* __restrict__ out) {
  __shared__ float red[BATCH];
  int m = threadIdx.x;
  red[m] = nll[m];
  __syncthreads();
  for (int k = 256; k > 0; k >>= 1) {
    if (m < k) red[m] += red[m + k];
    __syncthreads();
  }
  if (m == 0) out[0] = red[0] * (1.0f / BATCH);
}

extern "C" void kernel_launch(void* const* d_in, const int* in_sizes, int n_in,
                              void* d_out, int out_size, void* d_ws, size_t ws_size,
                              hipStream_t stream) {
  const float* x  = (const float*)d_in[0];
  const int*   gt = (const int*)d_in[1];
  const float* wt = (const float*)d_in[2];
  float* out = (float*)d_out;

  char* ws = (char*)d_ws;
  unsigned char* xq = (unsigned char*)ws;            //   262,144 B
  float* nx         = (float*)(ws + 262144);         //     2,048 B
  float* partial    = (float*)(ws + 264192);         // 1,601,536 B (512*782*4)
  float* tgt        = (float*)(ws + 1865728);        //     2,048 B
  float* nll        = (float*)(ws + 1867776);        //     2,048 B

  xquant<<<BATCH / 4, 256, 0, stream>>>(x, xq, nx);
  cosface_fused<<<4 * NT, 512, 0, stream>>>(xq, wt, gt, nx, partial, tgt);
  nll_rows<<<BATCH, 64, 0, stream>>>(partial, tgt, nll);
  reduce_mean<<<1, BATCH, 0, stream>>>(nll, out);
}

// Round 9
// 364.233 us; speedup vs baseline: 1.1965x; 1.1965x over previous
//
#include <hip/hip_runtime.h>
#include <hip/hip_bf16.h>

#define DIM 512
#define BATCH 512
#define CCLS 100000
#define BM 512    // all of M: wt fp32 is read EXACTLY ONCE chip-wide
#define BN 64
#define NT 1563   // ceil(100000/64)

typedef __attribute__((ext_vector_type(4))) float f32x4;

__device__ __forceinline__ void async_copy16(const unsigned char* g, unsigned char* l) {
  __builtin_amdgcn_global_load_lds((const __attribute__((address_space(1))) void*)g,
                                   (__attribute__((address_space(3))) void*)l, 16, 0, 0);
}

// One wave per row of x: quantize RAW x to fp8 e4m3 (norms divided out in the
// GEMM epilogue), emit nx[row] = |x_row|.
__global__ __launch_bounds__(256) void xquant(const float* __restrict__ x,
                                              unsigned char* __restrict__ xq,
                                              float* __restrict__ nx) {
  int wave = threadIdx.x >> 6;
  int lane = threadIdx.x & 63;
  int row = blockIdx.x * 4 + wave;           // 512 rows, 128 blocks
  const float4* src = (const float4*)(x + (size_t)row * DIM);
  float4 v0 = src[2 * lane];
  float4 v1 = src[2 * lane + 1];
  float ss = v0.x*v0.x + v0.y*v0.y + v0.z*v0.z + v0.w*v0.w
           + v1.x*v1.x + v1.y*v1.y + v1.z*v1.z + v1.w*v1.w;
  #pragma unroll
  for (int off = 32; off > 0; off >>= 1) ss += __shfl_xor(ss, off, 64);
  int p0 = __builtin_amdgcn_cvt_pk_fp8_f32(v0.x, v0.y, 0, false);
  p0     = __builtin_amdgcn_cvt_pk_fp8_f32(v0.z, v0.w, p0, true);
  int p1 = __builtin_amdgcn_cvt_pk_fp8_f32(v1.x, v1.y, 0, false);
  p1     = __builtin_amdgcn_cvt_pk_fp8_f32(v1.z, v1.w, p1, true);
  ((int2*)(xq + (size_t)row * DIM))[lane] = make_int2(p0, p1);
  if (lane == 0) nx[row] = fmaxf(sqrtf(ss), 1e-12f);
}

// Fused wt-quantize + 512x64 fp8 GEMM + CosFace epilogue.
// R8 post-mortem: fused variants were bound by LOGICAL fp32 wt traffic
// (mt-duplication: R7 410 MB, R8 800 MB). BM=512 removes duplication:
// each of the 1563 blocks reads its 64 wt rows (128 KB) once -> chip-wide
// wt stream = 205 MB = 32.5 us HBM floor, covered by MFMA.
// 1024 threads = 16 waves (8m x 2n), per-wave 64x32: acc[4][2] = 32 AGPR +
// ~64 arch = R7's proven no-spill envelope under the (1024,4) cap-128.
// Pipeline per K-tile (ONE barrier): ds_write B(kk+1) [dbuf half] ->
// issue A-asyncs(kk+1) [dbuf, full MFMA phase of cover] -> issue B-loads
// f(kk+2) -> 32 MFMA -> quant f(kk+2) -> __syncthreads.
// B-work only in waves 0-7; waves 8-15 never wait on wt loads.
__global__ __launch_bounds__(1024, 4) void cosface_fused(
    const unsigned char* __restrict__ xq,
    const float* __restrict__ wt,
    const int* __restrict__ gt,
    const float* __restrict__ nx,
    float* __restrict__ partial,
    float* __restrict__ tgt) {
  __shared__ __align__(16) unsigned char lds_a[2][BM * 128];   // 128 KB dbuf
  __shared__ __align__(16) unsigned char lds_b[2][BN * 128];   //  16 KB dbuf
  __shared__ float lds_rowsum[BM];
  __shared__ float lds_nx[BM];
  __shared__ float lds_nw[BN];
  __shared__ int lds_gt[BM];

  const int tid = threadIdx.x;
  const int lane = tid & 63;
  const int w = tid >> 6;          // wave 0..15
  const int wm = w >> 1;           // 0..7  (64-row slice)
  const int wn_ = w & 1;           // 0..1  (32-col slice)
  const int nt = blockIdx.x;       // 0..1562

  if (tid < BM) {
    lds_rowsum[tid] = 0.f;
    lds_gt[tid] = gt[tid];
    lds_nx[tid] = nx[tid];
  }

  // A staging: per K-tile 4096 chunks of 16B (512 rows x 8), 4/thread.
  // chunk c -> row m = c>>3, slot qs = c&7, content chunk qg = qs ^ (m&7).
  unsigned int oa[4];
  #pragma unroll
  for (int j = 0; j < 4; ++j) {
    int c = j * 1024 + tid;
    int m = c >> 3;
    int qg = (c & 7) ^ (m & 7);
    oa[j] = (unsigned int)m * DIM + qg * 16;
  }
#define STAGEA(sel, kk) do {                                                 \
    _Pragma("unroll")                                                        \
    for (int j = 0; j < 4; ++j)                                              \
      async_copy16(xq + oa[j] + (kk) * 128,                                  \
                   &lds_a[sel][(j * 1024 + w * 64) * 16]);                   \
  } while (0)

  // B source (fp32 wt): 512 chunk-slots, threads 0..511 own one each.
  const int r0 = tid >> 3;                 // class row 0..63 (tid<512)
  const int qg = (tid & 7) ^ (r0 & 7);
  int rowB = nt * BN + r0;
  if (rowB >= CCLS) rowB = CCLS - 1;       // clamp; excluded in epilogue
  const float* wsrc = wt + (size_t)rowB * DIM + qg * 16;

#define LOADB(K) do {                                                        \
    const float* p_ = wsrc + (K) * 128;                                      \
    a0 = *(const float4*)(p_);     a1 = *(const float4*)(p_ + 4);            \
    a2 = *(const float4*)(p_ + 8); a3 = *(const float4*)(p_ + 12);           \
  } while (0)

#define QUANT16() do {                                                       \
    a0.x*=16.f; a0.y*=16.f; a0.z*=16.f; a0.w*=16.f;                          \
    a1.x*=16.f; a1.y*=16.f; a1.z*=16.f; a1.w*=16.f;                          \
    a2.x*=16.f; a2.y*=16.f; a2.z*=16.f; a2.w*=16.f;                          \
    a3.x*=16.f; a3.y*=16.f; a3.z*=16.f; a3.w*=16.f;                          \
    ss0 += a0.x*a0.x + a0.y*a0.y + a0.z*a0.z + a0.w*a0.w                     \
         + a1.x*a1.x + a1.y*a1.y + a1.z*a1.z + a1.w*a1.w                     \
         + a2.x*a2.x + a2.y*a2.y + a2.z*a2.z + a2.w*a2.w                     \
         + a3.x*a3.x + a3.y*a3.y + a3.z*a3.z + a3.w*a3.w;                    \
    int q0_ = __builtin_amdgcn_cvt_pk_fp8_f32(a0.x, a0.y, 0, false);         \
    q0_     = __builtin_amdgcn_cvt_pk_fp8_f32(a0.z, a0.w, q0_, true);        \
    int q1_ = __builtin_amdgcn_cvt_pk_fp8_f32(a1.x, a1.y, 0, false);         \
    q1_     = __builtin_amdgcn_cvt_pk_fp8_f32(a1.z, a1.w, q1_, true);        \
    int q2_ = __builtin_amdgcn_cvt_pk_fp8_f32(a2.x, a2.y, 0, false);         \
    q2_     = __builtin_amdgcn_cvt_pk_fp8_f32(a2.z, a2.w, q2_, true);        \
    int q3_ = __builtin_amdgcn_cvt_pk_fp8_f32(a3.x, a3.y, 0, false);         \
    q3_     = __builtin_amdgcn_cvt_pk_fp8_f32(a3.z, a3.w, q3_, true);        \
    pA = make_int4(q0_, q1_, q2_, q3_);                                      \
  } while (0)

  f32x4 acc[4][2];
  #pragma unroll
  for (int i = 0; i < 4; ++i)
    #pragma unroll
    for (int j = 0; j < 2; ++j)
      acc[i][j] = (f32x4){0.f, 0.f, 0.f, 0.f};

  const int quad = lane >> 4;
  const int l15 = lane & 15;
  const int sw = l15 & 7;
  float4 a0, a1, a2, a3;
  int4 pA;
  float ss0 = 0.f;
  const bool bown = (tid < 512);

  // ---- Prologue: A(0) asyncs; B(0) quant+write; B(1) quant into regs.
  STAGEA(0, 0);
  if (bown) {
    LOADB(0);
    QUANT16();
    ((int4*)lds_b[0])[tid] = pA;
    LOADB(1);
    QUANT16();
  }
  __syncthreads();   // drains A(0) asyncs + B(0) writes; init visible

  #pragma unroll
  for (int kk = 0; kk < 4; ++kk) {
    const int cur = kk & 1;
    // Publish B(kk+1) into the half nobody reads this iter.
    if (kk < 3 && bown) {
      ((int4*)lds_b[cur ^ 1])[tid] = pA;
    }
    // Issue A(kk+1) asyncs -- full MFMA phase of cover before the barrier.
    if (kk < 3) STAGEA(cur ^ 1, kk + 1);
    // Issue B-loads f(kk+2) -- land during the MFMA cluster.
    if (kk < 2 && bown) LOADB(kk + 2);

    // Compute tile kk.
    #pragma unroll
    for (int s = 0; s < 4; ++s) {
      int g = s * 4 + quad;
      int cs = g >> 1;
      int h = (g & 1) * 8;
      long long af[4], bf[2];
      #pragma unroll
      for (int i = 0; i < 4; ++i)
        af[i] = *(const long long*)&lds_a[cur][(wm * 64 + i * 16 + l15) * 128 + ((cs ^ sw) * 16) + h];
      #pragma unroll
      for (int j = 0; j < 2; ++j)
        bf[j] = *(const long long*)&lds_b[cur][(wn_ * 32 + j * 16 + l15) * 128 + ((cs ^ sw) * 16) + h];
      #pragma unroll
      for (int i = 0; i < 4; ++i)
        #pragma unroll
        for (int j = 0; j < 2; ++j)
          acc[i][j] = __builtin_amdgcn_mfma_f32_16x16x32_fp8_fp8(af[i], bf[j], acc[i][j], 0, 0, 0);
    }

    // Quantize f(kk+2) (loads covered by the MFMA cluster just issued).
    if (kk < 2 && bown) QUANT16();
    if (kk < 3) __syncthreads();
  }
#undef STAGEA
#undef LOADB
#undef QUANT16

  // ---- nw: 8-lane group reduce, plain store (one owner per class row).
  if (bown) {
    ss0 += __shfl_xor(ss0, 1, 64);
    ss0 += __shfl_xor(ss0, 2, 64);
    ss0 += __shfl_xor(ss0, 4, 64);
    if ((lane & 7) == 0) lds_nw[r0] = ss0;
  }
  __syncthreads();

  // ---- Epilogue: cos = acc/(|16w|*|x|); logit = 64*cos (-22.4 at gt);
  // rowsum += sum_n exp(logit-64).
  float rnw[2];
  #pragma unroll
  for (int j = 0; j < 2; ++j)
    rnw[j] = 1.0f / fmaxf(sqrtf(lds_nw[wn_ * 32 + j * 16 + l15]), 1e-12f);
  #pragma unroll
  for (int i = 0; i < 4; ++i) {
    #pragma unroll
    for (int reg = 0; reg < 4; ++reg) {
      int m_loc = wm * 64 + i * 16 + quad * 4 + reg;
      int gtm = lds_gt[m_loc];
      float rx = 64.0f / lds_nx[m_loc];     // fold SCALE into the division
      float s = 0.f;
      #pragma unroll
      for (int j = 0; j < 2; ++j) {
        int n_g = nt * BN + wn_ * 32 + j * 16 + l15;
        float logit = acc[i][j][reg] * rnw[j] * rx;
        if (n_g == gtm) {
          logit -= 64.f * 0.35f;
          tgt[m_loc] = logit;
        }
        if (n_g < CCLS) s += __expf(logit - 64.f);
      }
      #pragma unroll
      for (int off = 1; off < 16; off <<= 1) s += __shfl_xor(s, off, 64);
      if (l15 == 0) atomicAdd(&lds_rowsum[m_loc], s);
    }
  }
  __syncthreads();
  if (tid < BM)
    partial[(size_t)tid * NT + nt] = lds_rowsum[tid];
}

// One wave per row m: sum partial[m][0..NT) (contiguous), emit nll[m].
__global__ __launch_bounds__(64) void nll_rows(const float* __restrict__ partial,
                                               const float* __restrict__ tgt,
                                               float* __restrict__ nll) {
  int m = blockIdx.x;
  int lane = threadIdx.x;
  const float* row = partial + (size_t)m * NT;
  float s = 0.f;
  for (int t = lane; t < NT; t += 64) s += row[t];
  #pragma unroll
  for (int off = 32; off > 0; off >>= 1) s += __shfl_xor(s, off, 64);
  if (lane == 0) nll[m] = (logf(s) + 64.f) - tgt[m];
}

__global__ __launch_bounds__(512) void reduce_mean(const float* __restrict__ nll,
                                                   float* __restrict__ out) {
  __shared__ float red[BATCH];
  int m = threadIdx.x;
  red[m] = nll[m];
  __syncthreads();
  for (int k = 256; k > 0; k >>= 1) {
    if (m < k) red[m] += red[m + k];
    __syncthreads();
  }
  if (m == 0) out[0] = red[0] * (1.0f / BATCH);
}

extern "C" void kernel_launch(void* const* d_in, const int* in_sizes, int n_in,
                              void* d_out, int out_size, void* d_ws, size_t ws_size,
                              hipStream_t stream) {
  const float* x  = (const float*)d_in[0];
  const int*   gt = (const int*)d_in[1];
  const float* wt = (const float*)d_in[2];
  float* out = (float*)d_out;

  char* ws = (char*)d_ws;
  unsigned char* xq = (unsigned char*)ws;            //   262,144 B
  float* nx         = (float*)(ws + 262144);         //     2,048 B
  float* partial    = (float*)(ws + 264192);         // 3,201,024 B (512*1563*4)
  float* tgt        = (float*)(ws + 3465216);        //     2,048 B
  float* nll        = (float*)(ws + 3467264);        //     2,048 B

  xquant<<<BATCH / 4, 256, 0, stream>>>(x, xq, nx);
  cosface_fused<<<NT, 1024, 0, stream>>>(xq, wt, gt, nx, partial, tgt);
  nll_rows<<<BATCH, 64, 0, stream>>>(partial, tgt, nll);
  reduce_mean<<<1, BATCH, 0, stream>>>(nll, out);
}